// Round 11
// baseline (2312.598 us; speedup 1.0000x reference)
//
#include <hip/hip_runtime.h>
#include <cmath>

typedef unsigned long long u64;

#define PRE_TOPN 12000
#define POST_TOPN 2000
#define SORTN 32768
#define TILE 8192
#define NTILE (SORTN / TILE)   // 4 tiles per batch
#define NBLK 188               // 64-bit column blocks covering 12032
#define PADN (NBLK * 64)       // 12032
// triangular bitmap: column-block cb stores rows 0..(cb+1)*64-1
// triOff(cb) = 32*cb*(cb+1); total words per batch:
#define TRI_WORDS (32 * (NBLK - 1) * NBLK + NBLK * 64)  // 1,137,024

__device__ inline u64 shfl_u64(u64 v, int lane) {
    int lo = __shfl((int)(unsigned)(v & 0xffffffffULL), lane);
    int hi = __shfl((int)(unsigned)(v >> 32), lane);
    return ((u64)(unsigned)hi << 32) | (u64)(unsigned)lo;
}

__device__ inline u64 shfl_xor_u64(u64 v, int mask) {
    int lo = __shfl_xor((int)(unsigned)(v & 0xffffffffULL), mask);
    int hi = __shfl_xor((int)(unsigned)(v >> 32), mask);
    return ((u64)(unsigned)hi << 32) | (u64)(unsigned)lo;
}

// ---------------------------------------------------------------------------
// Kernel 1: decode boxes (exact fp32 op order, no FMA contraction, exp via
// double) and pack sort keys. key = (~score_bits)<<32 | idx.
// ---------------------------------------------------------------------------
__global__ void decode_pack(const float* __restrict__ anchors,
                            const float* __restrict__ deltas,
                            const float* __restrict__ scores,
                            float* __restrict__ boxes,
                            u64* __restrict__ keys,
                            int N) {
#pragma clang fp contract(off)
    int n = blockIdx.x * blockDim.x + threadIdx.x;
    int b = blockIdx.y;
    if (n >= SORTN) return;
    u64* kb = keys + (size_t)b * SORTN;
    if (n < N) {
        float a0 = anchors[n * 4 + 0];
        float a1 = anchors[n * 4 + 1];
        float a2 = anchors[n * 4 + 2];
        float a3 = anchors[n * 4 + 3];
        float w = (a2 - a0) + 1.0f;
        float h = (a3 - a1) + 1.0f;
        float cx = a0 + 0.5f * w;
        float cy = a1 + 0.5f * h;
        const float* d = deltas + ((size_t)b * N + n) * 4;
        float dx = d[0], dy = d[1], dw = d[2], dh = d[3];
        float px = cx + w * dx;
        float py = cy + h * dy;
        float pw = (float)::exp((double)dw) * w;
        float ph = (float)::exp((double)dh) * h;
        float* bb = boxes + ((size_t)b * N + n) * 4;
        bb[0] = px - 0.5f * pw;
        bb[1] = py - 0.5f * ph;
        bb[2] = px + 0.5f * (pw - 2.0f);
        bb[3] = py + 0.5f * (ph - 2.0f);
        unsigned int sb = __float_as_uint(scores[(size_t)b * N + n]);
        kb[n] = ((u64)(~sb) << 32) | (u64)(unsigned int)n;
    } else {
        kb[n] = ~0ULL;
    }
}

// ---------------------------------------------------------------------------
// Hybrid bitonic sort (unchanged).
// ---------------------------------------------------------------------------
__global__ __launch_bounds__(1024) void bitonic_local_sort(u64* __restrict__ keys) {
    __shared__ u64 sk[TILE];
    int tile = blockIdx.x;
    u64* kb = keys + (size_t)tile * TILE;
    int base = (tile % NTILE) * TILE;
    for (int i = threadIdx.x; i < TILE; i += 1024) sk[i] = kb[i];
    __syncthreads();
    for (int k = 2; k <= TILE; k <<= 1) {
        for (int j = k >> 1; j > 0; j >>= 1) {
            for (int t = threadIdx.x; t < TILE / 2; t += 1024) {
                int i = ((t & ~(j - 1)) << 1) | (t & (j - 1));
                int ixj = i | j;
                u64 a = sk[i];
                u64 c = sk[ixj];
                bool up = (((base + i) & k) == 0);
                if ((a > c) == up) { sk[i] = c; sk[ixj] = a; }
            }
            __syncthreads();
        }
    }
    for (int i = threadIdx.x; i < TILE; i += 1024) kb[i] = sk[i];
}

__global__ void bitonic_global_step(u64* __restrict__ keys, int k, int j) {
    int t = blockIdx.x * blockDim.x + threadIdx.x;
    int b = t / (SORTN / 2);
    int s = t % (SORTN / 2);
    int i = ((s & ~(j - 1)) << 1) | (s & (j - 1));
    int ixj = i | j;
    u64* kb = keys + (size_t)b * SORTN;
    u64 a = kb[i];
    u64 c = kb[ixj];
    bool up = ((i & k) == 0);
    if ((a > c) == up) { kb[i] = c; kb[ixj] = a; }
}

__global__ __launch_bounds__(1024) void bitonic_local_merge(u64* __restrict__ keys, int k) {
    __shared__ u64 sk[TILE];
    int tile = blockIdx.x;
    u64* kb = keys + (size_t)tile * TILE;
    int base = (tile % NTILE) * TILE;
    bool up = ((base & k) == 0);
    for (int i = threadIdx.x; i < TILE; i += 1024) sk[i] = kb[i];
    __syncthreads();
    for (int j = TILE / 2; j > 0; j >>= 1) {
        for (int t = threadIdx.x; t < TILE / 2; t += 1024) {
            int i = ((t & ~(j - 1)) << 1) | (t & (j - 1));
            int ixj = i | j;
            u64 a = sk[i];
            u64 c = sk[ixj];
            if ((a > c) == up) { sk[i] = c; sk[ixj] = a; }
        }
        __syncthreads();
    }
    for (int i = threadIdx.x; i < TILE; i += 1024) kb[i] = sk[i];
}

// ---------------------------------------------------------------------------
// Gather sorted top-PADN boxes. Pad rows get far-away degenerate boxes.
// ---------------------------------------------------------------------------
__global__ void gather_sorted(const float* __restrict__ boxes,
                              const u64* __restrict__ keys,
                              float4* __restrict__ sbox, int N) {
    int r = blockIdx.x * 256 + threadIdx.x;
    int b = blockIdx.y;
    if (r >= PADN) return;
    float4 v;
    if (r < PRE_TOPN) {
        u64 key = keys[(size_t)b * SORTN + r];
        int n = (int)(unsigned)(key & 0xffffffffULL);
        v = ((const float4*)boxes)[(size_t)b * N + n];
    } else {
        v = make_float4(-4e8f, -4e8f, -4e8f, -4e8f);
    }
    sbox[(size_t)b * PADN + r] = v;
}

// ---------------------------------------------------------------------------
// Build suppression bitmap — round-6 LDS-staged form, TWO ROWS PER THREAD.
//   64 column boxes + areas staged in LDS; each thread computes rows r0 and
//   r0+256 against them. Same VALU work per pair as round 6, but each LDS
//   read pair feeds 2 IoUs and every j-iteration carries 2 independent
//   dependency chains -> ~2x the issuable VALU between lgkmcnt waits
//   (round 6 measured ~54% issue efficiency at 36 VGPR). launch_bounds
//   (256,4) caps VGPR at 128 to prevent a round-8-style blowup (184 VGPR,
//   11% occupancy with 4 rows).
// Predicate (division-free, bit-exact vs reference, validated r5-r10):
//   RN_f32(inter/un) > 0.7f  <=>  (double)inter >= MD*(double)un,
//   MD = 0.7f + 2^-25 (25-bit x 24-bit product exact in f64).
//   NOTE: do NOT precompute x2+1: RN((x2+1)-x1) != RN((x2-x1)+1).
// Grid (cb, 24 chunks of 512 rows, B); early-exit if 8*chunk > cb.
// Loads clamp r to PADN-1; stores use unclamped r with r < (cb+1)*64.
// ---------------------------------------------------------------------------
__global__ __launch_bounds__(256, 4) void build_bitmap(const float4* __restrict__ sbox,
                                                       u64* __restrict__ bitmap) {
#pragma clang fp contract(off)
    const double MD = (double)0.7f + 0x1p-25;   // exact midpoint multiplier
    int cb = blockIdx.x;        // column block 0..NBLK-1
    int chunk = blockIdx.y;     // row chunk (512 rows) 0..23
    int b = blockIdx.z;
    if (chunk * 8 > cb) return; // chunk's first row >= (cb+1)*64 -> empty
    int tid = threadIdx.x;

    __shared__ float4 cbox[64];
    __shared__ float carea[64];
    const float4* sb = sbox + (size_t)b * PADN;
    if (tid < 64) {
        float4 c4 = sb[cb * 64 + tid];
        cbox[tid] = c4;
        carea[tid] = ((c4.z - c4.x) + 1.0f) * ((c4.w - c4.y) + 1.0f);
    }
    int r0 = chunk * 512 + tid;           // rows r0 and r0+256
    int rc0 = min(r0,       PADN - 1);
    int rc1 = min(r0 + 256, PADN - 1);
    float4 a4 = sb[rc0];
    float4 b4 = sb[rc1];
    float aa = ((a4.z - a4.x) + 1.0f) * ((a4.w - a4.y) + 1.0f);
    float ba = ((b4.z - b4.x) + 1.0f) * ((b4.w - b4.y) + 1.0f);
    __syncthreads();

    unsigned alo = 0, ahi = 0, blo = 0, bhi = 0;
#pragma unroll
    for (int j = 0; j < 64; ++j) {
        float4 cj = cbox[j];
        float caj = carea[j];
        // row A
        {
            float xx1 = fmaxf(a4.x, cj.x);
            float yy1 = fmaxf(a4.y, cj.y);
            float xx2 = fminf(a4.z, cj.z);
            float yy2 = fminf(a4.w, cj.w);
            float w = fmaxf((xx2 - xx1) + 1.0f, 0.0f);
            float h = fmaxf((yy2 - yy1) + 1.0f, 0.0f);
            float inter = w * h;
            float un = (aa + caj) - inter;
            bool sup = ((double)inter >= MD * (double)un);
            if (j < 32) alo |= ((unsigned)sup) << j;
            else        ahi |= ((unsigned)sup) << (j - 32);
        }
        // row B
        {
            float xx1 = fmaxf(b4.x, cj.x);
            float yy1 = fmaxf(b4.y, cj.y);
            float xx2 = fminf(b4.z, cj.z);
            float yy2 = fminf(b4.w, cj.w);
            float w = fmaxf((xx2 - xx1) + 1.0f, 0.0f);
            float h = fmaxf((yy2 - yy1) + 1.0f, 0.0f);
            float inter = w * h;
            float un = (ba + caj) - inter;
            bool sup = ((double)inter >= MD * (double)un);
            if (j < 32) blo |= ((unsigned)sup) << j;
            else        bhi |= ((unsigned)sup) << (j - 32);
        }
    }

    int cbase = cb * 64;
    int lim = cbase + 64;
    u64 wA = ((u64)ahi << 32) | (u64)alo;
    u64 wB = ((u64)bhi << 32) | (u64)blo;
    int d0 = r0 - cbase;
    int d1 = r0 + 256 - cbase;
    if (d0 >= 0 && d0 < 64) wA &= ~((2ULL << d0) - 1ULL);   // upper triangle only
    if (d1 >= 0 && d1 < 64) wB &= ~((2ULL << d1) - 1ULL);

    u64* dst = bitmap + (size_t)b * TRI_WORDS + (size_t)32 * cb * (cb + 1);
    if (r0       < lim) dst[r0]       = wA;
    if (r0 + 256 < lim) dst[r0 + 256] = wB;
}

// ---------------------------------------------------------------------------
// Sequential scan, deferred-OR (round-6 version, plain cached loads).
// ---------------------------------------------------------------------------
__global__ __launch_bounds__(256) void scan_nms(const float4* __restrict__ sbox,
                                                const u64* __restrict__ bitmap,
                                                float* __restrict__ out) {
    int b = blockIdx.x;
    int tid = threadIdx.x;
    int lane = tid & 63;
    int wv = tid >> 6;
    __shared__ int picks_lds[POST_TOPN];   // 8 KB
    __shared__ u64 s_partial[4];
    __shared__ int s_K;

    if (tid == 0) s_K = 0;
    __syncthreads();

    const u64* bm = bitmap + (size_t)b * TRI_WORDS;

    for (int rb = 0; rb < NBLK; ++rb) {
        int K = s_K;                       // uniform (post-barrier)
        if (K >= POST_TOPN) break;
        const u64* slab = bm + (size_t)32 * rb * (rb + 1);  // rows 0..(rb+1)*64-1
        int base = rb * 64;

        // wave-0 prefetch (issues before the gather's waits)
        u64 myrow = 0;
        float4 mybox = make_float4(0.f, 0.f, 0.f, 0.f);
        if (wv == 0) {
            myrow = slab[base + lane];
            mybox = sbox[(size_t)b * PADN + base + lane];
        }

        // deferred gather: OR suppression words of all prior picks
        u64 sup = 0;
        {
            int t = tid;
            for (; t + 768 < K; t += 1024) {
                u64 g0 = slab[picks_lds[t]];
                u64 g1 = slab[picks_lds[t + 256]];
                u64 g2 = slab[picks_lds[t + 512]];
                u64 g3 = slab[picks_lds[t + 768]];
                sup |= (g0 | g1) | (g2 | g3);
            }
            for (; t < K; t += 256) sup |= slab[picks_lds[t]];
        }
        for (int off = 1; off < 64; off <<= 1) sup |= shfl_xor_u64(sup, off);
        if (lane == 0) s_partial[wv] = sup;
        __syncthreads();

        if (wv == 0) {
            u64 total = s_partial[0] | s_partial[1] | s_partial[2] | s_partial[3];
            if (rb == NBLK - 1) total |= 0xFFFFFFFF00000000ULL;   // pad rows >= 12000
            int c = lane;
            u64 alive = ~total;
            u64 picks = 0;
            u64 cur = alive;
            while (cur) {
                int i = __ffsll((long long)cur) - 1;
                picks |= 1ULL << i;
                u64 row = shfl_u64(myrow, i);
                alive &= ~row;
                cur = alive & ~((2ULL << i) - 1ULL);
            }
            int avail = POST_TOPN - K;
            int np = __popcll(picks);
            while (np > avail) {                       // truncate latest picks
                picks &= ~(1ULL << (63 - __clzll(picks)));
                --np;
            }
            if ((picks >> c) & 1ULL) {
                int rank = __popcll(picks & ((1ULL << c) - 1ULL));
                picks_lds[K + rank] = base + c;
                float* o = out + ((size_t)b * POST_TOPN + K + rank) * 5;
                o[0] = (float)b; o[1] = mybox.x; o[2] = mybox.y; o[3] = mybox.z; o[4] = mybox.w;
            }
            if (c == 0) s_K = K + np;
        }
        __syncthreads();
    }

    int K = s_K;
    for (int r = K + tid; r < POST_TOPN; r += 256) {
        float* o = out + ((size_t)b * POST_TOPN + r) * 5;
        o[0] = 0.0f; o[1] = 0.0f; o[2] = 0.0f; o[3] = 0.0f; o[4] = 0.0f;
    }
}

// ---------------------------------------------------------------------------
// Fallback (round-2) NMS kernel — used only if ws_size can't hold the bitmap.
// ---------------------------------------------------------------------------
__global__ __launch_bounds__(1024) void nms_kernel(const float* __restrict__ boxes,
                                                   const u64* __restrict__ keys,
                                                   float* __restrict__ out,
                                                   int N) {
#pragma clang fp contract(off)
    __shared__ float4 kbox[POST_TOPN];
    __shared__ float kar[POST_TOPN];
    __shared__ float4 cbox[64];
    __shared__ float car_s[64];
    __shared__ int supp[64];
    __shared__ int s_cnt;

    int b = blockIdx.x;
    int tid = threadIdx.x;
    const u64* kb = keys + (size_t)b * SORTN;
    const float* bb = boxes + (size_t)b * N * 4;

    if (tid == 0) s_cnt = 0;
    __syncthreads();

    for (int start = 0; start < PRE_TOPN; start += 64) {
        int K = s_cnt;
        if (K >= POST_TOPN) break;
        int csize = min(64, PRE_TOPN - start);

        if (tid < 64) {
            int c = tid;
            if (c < csize) {
                u64 key = kb[start + c];
                int n = (int)(unsigned int)(key & 0xFFFFFFFFULL);
                const float* p = bb + (size_t)n * 4;
                float x1 = p[0], y1 = p[1], x2 = p[2], y2 = p[3];
                cbox[c] = make_float4(x1, y1, x2, y2);
                car_s[c] = ((x2 - x1) + 1.0f) * ((y2 - y1) + 1.0f);
            }
            supp[c] = 0;
        }
        __syncthreads();

        {
            int c = tid & 63;
            int sl = tid >> 6;
            if (c < csize) {
                float4 me = cbox[c];
                float ar = car_s[c];
                int flag = 0;
                for (int kk = sl; kk < K; kk += 16) {
                    float4 k0 = kbox[kk];
                    float a0 = kar[kk];
                    float xx1 = fmaxf(k0.x, me.x);
                    float yy1 = fmaxf(k0.y, me.y);
                    float xx2 = fminf(k0.z, me.z);
                    float yy2 = fminf(k0.w, me.w);
                    float w0 = fmaxf((xx2 - xx1) + 1.0f, 0.0f);
                    float h0 = fmaxf((yy2 - yy1) + 1.0f, 0.0f);
                    float inter0 = w0 * h0;
                    float iou0 = inter0 / ((a0 + ar) - inter0);
                    if (iou0 > 0.7f) { flag = 1; break; }
                }
                if (flag) supp[c] = 1;
            }
        }
        __syncthreads();

        if (tid < 64) {
            int c = tid;
            bool alive = (c < csize) && (supp[c] == 0);
            float4 me = cbox[c];
            float ar = car_s[c];
            int cnt = K;
            u64 m = __ballot(alive);
            while (m != 0 && cnt < POST_TOPN) {
                int i = __ffsll((unsigned long long)m) - 1;
                float ix1 = __shfl(me.x, i);
                float iy1 = __shfl(me.y, i);
                float ix2 = __shfl(me.z, i);
                float iy2 = __shfl(me.w, i);
                float iar = __shfl(ar, i);
                if (c == i) {
                    kbox[cnt] = me;
                    kar[cnt] = ar;
                    float* o = out + ((size_t)b * POST_TOPN + cnt) * 5;
                    o[0] = (float)b; o[1] = me.x; o[2] = me.y; o[3] = me.z; o[4] = me.w;
                }
                if (alive && c > i) {
                    float xx1 = fmaxf(ix1, me.x);
                    float yy1 = fmaxf(iy1, me.y);
                    float xx2 = fminf(ix2, me.z);
                    float yy2 = fminf(iy2, me.w);
                    float w = fmaxf((xx2 - xx1) + 1.0f, 0.0f);
                    float h = fmaxf((yy2 - yy1) + 1.0f, 0.0f);
                    float inter = w * h;
                    float iou = inter / ((iar + ar) - inter);
                    if (iou > 0.7f) alive = false;
                }
                cnt++;
                m = __ballot(alive);
                u64 clearmask = (2ULL << i) - 1ULL;
                m &= ~clearmask;
            }
            if (c == 0) s_cnt = cnt;
        }
        __syncthreads();
    }

    __syncthreads();
    int K = s_cnt;
    for (int r = K + tid; r < POST_TOPN; r += (int)blockDim.x) {
        float* o = out + ((size_t)b * POST_TOPN + r) * 5;
        o[0] = 0.0f; o[1] = 0.0f; o[2] = 0.0f; o[3] = 0.0f; o[4] = 0.0f;
    }
}

// ---------------------------------------------------------------------------
extern "C" void kernel_launch(void* const* d_in, const int* in_sizes, int n_in,
                              void* d_out, int out_size, void* d_ws, size_t ws_size,
                              hipStream_t stream) {
    const float* anchors = (const float*)d_in[0];
    const float* deltas  = (const float*)d_in[1];
    const float* scores  = (const float*)d_in[2];
    float* out = (float*)d_out;

    int N = in_sizes[0] / 4;           // 27380
    int B = in_sizes[2] / N;           // 8

    size_t off = 0;
    auto take = [&](size_t bytes) { size_t o = off; off = (off + bytes + 255) & ~(size_t)255; return o; };
    size_t boxesOff  = take((size_t)B * N * 4 * sizeof(float));
    size_t keysOff   = take((size_t)B * SORTN * sizeof(u64));
    size_t sboxOff   = take((size_t)B * PADN * sizeof(float4));
    size_t bitmapOff = take((size_t)B * TRI_WORDS * sizeof(u64));
    bool bitmap_path = (off <= ws_size);

    float* boxes = (float*)((char*)d_ws + boxesOff);
    u64*   keys  = (u64*)((char*)d_ws + keysOff);

    dim3 g1((unsigned)((SORTN + 255) / 256), (unsigned)B);
    decode_pack<<<g1, 256, 0, stream>>>(anchors, deltas, scores, boxes, keys, N);

    int ntiles = B * NTILE;
    bitonic_local_sort<<<ntiles, 1024, 0, stream>>>(keys);
    int gsteps = B * (SORTN / 2) / 256;
    bitonic_global_step<<<gsteps, 256, 0, stream>>>(keys, 2 * TILE, TILE);
    bitonic_local_merge<<<ntiles, 1024, 0, stream>>>(keys, 2 * TILE);
    bitonic_global_step<<<gsteps, 256, 0, stream>>>(keys, 4 * TILE, 2 * TILE);
    bitonic_global_step<<<gsteps, 256, 0, stream>>>(keys, 4 * TILE, TILE);
    bitonic_local_merge<<<ntiles, 1024, 0, stream>>>(keys, 4 * TILE);

    if (bitmap_path) {
        float4* sbox = (float4*)((char*)d_ws + sboxOff);
        u64* bitmap  = (u64*)((char*)d_ws + bitmapOff);
        dim3 gg((unsigned)((PADN + 255) / 256), (unsigned)B);
        gather_sorted<<<gg, 256, 0, stream>>>(boxes, keys, sbox, N);
        dim3 gb((unsigned)NBLK, 24u, (unsigned)B);
        build_bitmap<<<gb, 256, 0, stream>>>(sbox, bitmap);
        scan_nms<<<B, 256, 0, stream>>>(sbox, bitmap, out);
    } else {
        nms_kernel<<<B, 1024, 0, stream>>>(boxes, keys, out, N);
    }
}